// Round 2
// baseline (216.806 us; speedup 1.0000x reference)
//
#include <hip/hip_runtime.h>

constexpr int B = 32;
constexpr int N = 32 * 32 * 32 + 1;   // 32769
constexpr int K = 32 * 3 * 3;         // 288
constexpr int KHALF = K / 2;          // 144

using i4 = __attribute__((ext_vector_type(4))) int;
using f4 = __attribute__((ext_vector_type(4))) float;

// ---------------------------------------------------------------------------
// Kernel 1: transpose x (B,N) -> xT (N,B). 32x32 tiles via LDS.
// ---------------------------------------------------------------------------
__global__ __launch_bounds__(256) void transpose_x_kernel(
    const float* __restrict__ x, float* __restrict__ xT) {
  __shared__ float tile[32][33];
  const int n0 = blockIdx.x * 32;
  const int t  = threadIdx.x;
  const int lb = t & 31;   // 0..31
  const int lr = t >> 5;   // 0..7
#pragma unroll
  for (int i = 0; i < 4; ++i) {
    const int b = lr + i * 8;
    const int n = n0 + lb;
    float v = 0.f;
    if (n < N) v = x[(size_t)b * N + n];   // coalesced over lb
    tile[lb][b] = v;
  }
  __syncthreads();
#pragma unroll
  for (int i = 0; i < 4; ++i) {
    const int nl = lr + i * 8;
    const int n  = n0 + nl;
    if (n < N) xT[(size_t)n * B + lb] = tile[nl][lb];  // coalesced over lb
  }
}

// ---------------------------------------------------------------------------
// Kernel 2: gather-dot with K split in two halves (blockIdx.y selects half).
// yTh[half][n][b] = sum_{k in half} xT[cols[n,k]][b] * vals[n,k]
// 8-lane group per n, lane owns 4 consecutive b. 32 n per block.
// cols/vals are streamed non-temporally (read-once) so xT stays L2-resident.
// ---------------------------------------------------------------------------
__global__ __launch_bounds__(256) void gather_dot_ksplit_kernel(
    const float* __restrict__ xT, const float* __restrict__ vals,
    const int* __restrict__ cols, float* __restrict__ yT0,
    float* __restrict__ yT1) {
  const int t    = threadIdx.x;
  const int lane = t & 63;
  const int wave = t >> 6;
  const int g    = lane >> 3;        // 0..7 : n within wave
  const int bq   = lane & 7;         // 0..7 : b quad
  const int n    = blockIdx.x * 32 + wave * 8 + g;
  if (n >= N) return;

  const int  k0   = blockIdx.y * KHALF;
  const int* __restrict__ crow   = cols + (size_t)n * K + k0;
  const float* __restrict__ vrow = vals + (size_t)n * K + k0;

  f4 acc0 = {0.f, 0.f, 0.f, 0.f};
  f4 acc1 = {0.f, 0.f, 0.f, 0.f};

#pragma unroll 4
  for (int k = 0; k < KHALF; k += 8) {
    const i4 cA = __builtin_nontemporal_load((const i4*)(crow + k));
    const f4 vA = __builtin_nontemporal_load((const f4*)(vrow + k));
    const i4 cB = __builtin_nontemporal_load((const i4*)(crow + k + 4));
    const f4 vB = __builtin_nontemporal_load((const f4*)(vrow + k + 4));

    const f4 xA0 = *reinterpret_cast<const f4*>(xT + (size_t)cA.x * B + bq * 4);
    const f4 xA1 = *reinterpret_cast<const f4*>(xT + (size_t)cA.y * B + bq * 4);
    const f4 xA2 = *reinterpret_cast<const f4*>(xT + (size_t)cA.z * B + bq * 4);
    const f4 xA3 = *reinterpret_cast<const f4*>(xT + (size_t)cA.w * B + bq * 4);
    const f4 xB0 = *reinterpret_cast<const f4*>(xT + (size_t)cB.x * B + bq * 4);
    const f4 xB1 = *reinterpret_cast<const f4*>(xT + (size_t)cB.y * B + bq * 4);
    const f4 xB2 = *reinterpret_cast<const f4*>(xT + (size_t)cB.z * B + bq * 4);
    const f4 xB3 = *reinterpret_cast<const f4*>(xT + (size_t)cB.w * B + bq * 4);

    acc0 += xA0 * vA.x;
    acc0 += xA1 * vA.y;
    acc0 += xA2 * vA.z;
    acc0 += xA3 * vA.w;
    acc1 += xB0 * vB.x;
    acc1 += xB1 * vB.y;
    acc1 += xB2 * vB.z;
    acc1 += xB3 * vB.w;
  }

  acc0 += acc1;
  float* __restrict__ out = (blockIdx.y == 0) ? yT0 : yT1;
  *reinterpret_cast<f4*>(out + (size_t)n * B + bq * 4) = acc0;
}

// ---------------------------------------------------------------------------
// Kernel 3: y (B,N) = transpose(yT0 + yT1).
// ---------------------------------------------------------------------------
__global__ __launch_bounds__(256) void transpose_y_sum_kernel(
    const float* __restrict__ yT0, const float* __restrict__ yT1,
    float* __restrict__ y) {
  __shared__ float tile[32][33];
  const int n0 = blockIdx.x * 32;
  const int t  = threadIdx.x;
  const int lb = t & 31;
  const int lr = t >> 5;
#pragma unroll
  for (int i = 0; i < 4; ++i) {
    const int nl = lr + i * 8;
    const int n  = n0 + nl;
    float v = 0.f;
    if (n < N) {
      const size_t idx = (size_t)n * B + lb;
      v = yT0[idx] + yT1[idx];   // coalesced over lb
    }
    tile[nl][lb] = v;
  }
  __syncthreads();
#pragma unroll
  for (int i = 0; i < 4; ++i) {
    const int b = lr + i * 8;
    const int n = n0 + lb;
    if (n < N) y[(size_t)b * N + n] = tile[lb][b];  // coalesced over lb
  }
}

// ---------------------------------------------------------------------------
// Fallback (ws too small): direct strided gather, correct but slow.
// ---------------------------------------------------------------------------
__global__ __launch_bounds__(256) void gather_dot_fallback(
    const float* __restrict__ x, const float* __restrict__ vals,
    const int* __restrict__ cols, float* __restrict__ y) {
  const int t    = threadIdx.x;
  const int lane = t & 63;
  const int wave = t >> 6;
  const int g    = lane >> 3;
  const int bq   = lane & 7;
  const int n    = blockIdx.x * 32 + wave * 8 + g;
  if (n >= N) return;
  const int*   crow = cols + (size_t)n * K;
  const float* vrow = vals + (size_t)n * K;
  float4 acc = make_float4(0.f, 0.f, 0.f, 0.f);
  for (int k = 0; k < K; ++k) {
    const int   c = crow[k];
    const float v = vrow[k];
    acc.x += x[(size_t)(bq * 4 + 0) * N + c] * v;
    acc.y += x[(size_t)(bq * 4 + 1) * N + c] * v;
    acc.z += x[(size_t)(bq * 4 + 2) * N + c] * v;
    acc.w += x[(size_t)(bq * 4 + 3) * N + c] * v;
  }
  y[(size_t)(bq * 4 + 0) * N + n] = acc.x;
  y[(size_t)(bq * 4 + 1) * N + n] = acc.y;
  y[(size_t)(bq * 4 + 2) * N + n] = acc.z;
  y[(size_t)(bq * 4 + 3) * N + n] = acc.w;
}

extern "C" void kernel_launch(void* const* d_in, const int* in_sizes, int n_in,
                              void* d_out, int out_size, void* d_ws, size_t ws_size,
                              hipStream_t stream) {
  const float* x    = (const float*)d_in[0];   // x_affine (B,N)
  const float* vals = (const float*)d_in[1];   // (N,K)
  const int*   cols = (const int*)d_in[2];     // (N,K)
  float*       y    = (float*)d_out;           // (B,N)

  const size_t nb_elems = (size_t)N * B;                 // 4.19 MB
  const size_t need     = 3 * nb_elems * sizeof(float);  // xT + yT0 + yT1

  const int nblocks = (N + 31) / 32;   // 1025

  if (ws_size >= need) {
    float* xT  = (float*)d_ws;
    float* yT0 = xT + nb_elems;
    float* yT1 = yT0 + nb_elems;
    transpose_x_kernel<<<nblocks, 256, 0, stream>>>(x, xT);
    dim3 grid(nblocks, 2);
    gather_dot_ksplit_kernel<<<grid, 256, 0, stream>>>(xT, vals, cols, yT0, yT1);
    transpose_y_sum_kernel<<<nblocks, 256, 0, stream>>>(yT0, yT1, y);
  } else {
    gather_dot_fallback<<<nblocks, 256, 0, stream>>>(x, vals, cols, y);
  }
}

// Round 3
// 176.187 us; speedup vs baseline: 1.2305x; 1.2305x over previous
//
#include <hip/hip_runtime.h>

constexpr int B = 32;
constexpr int N = 32 * 32 * 32 + 1;   // 32769
constexpr int K = 32 * 3 * 3;         // 288

using i4 = __attribute__((ext_vector_type(4))) int;
using f4 = __attribute__((ext_vector_type(4))) float;

// ---------------------------------------------------------------------------
// Kernel 1: transpose x (B,N) -> xT (N,B). 32x32 tiles via LDS.
// ---------------------------------------------------------------------------
__global__ __launch_bounds__(256) void transpose_x_kernel(
    const float* __restrict__ x, float* __restrict__ xT) {
  __shared__ float tile[32][33];
  const int n0 = blockIdx.x * 32;
  const int t  = threadIdx.x;
  const int lb = t & 31;   // 0..31
  const int lr = t >> 5;   // 0..7
#pragma unroll
  for (int i = 0; i < 4; ++i) {
    const int b = lr + i * 8;
    const int n = n0 + lb;
    float v = 0.f;
    if (n < N) v = x[(size_t)b * N + n];   // coalesced over lb
    tile[lb][b] = v;
  }
  __syncthreads();
#pragma unroll
  for (int i = 0; i < 4; ++i) {
    const int nl = lr + i * 8;
    const int n  = n0 + nl;
    if (n < N) xT[(size_t)n * B + lb] = tile[nl][lb];  // coalesced over lb
  }
}

// ---------------------------------------------------------------------------
// Kernel 2: gather-dot with cols staged in LDS via global_load_lds.
// yT[n][b] = sum_k xT[cols[n,k]][b] * vals[n,k]
// 8-lane group per n (32 n / 256-thread block); lane owns 4 consecutive b.
// Group g rotates its k-start by g*8 so concurrent LDS reads are spread
// across banks (stride-288 rows would otherwise alias to the same banks).
// ---------------------------------------------------------------------------
__global__ __launch_bounds__(256) void gather_dot_lds_kernel(
    const float* __restrict__ xT, const float* __restrict__ vals,
    const int* __restrict__ cols, float* __restrict__ yT) {
  __shared__ int scols[32 * K];              // 36864 B
  const int t    = threadIdx.x;
  const int lane = t & 63;
  const int wave = t >> 6;
  const int g    = lane >> 3;        // 0..7 : n within wave
  const int bq   = lane & 7;         // 0..7 : b quad
  const int n0   = blockIdx.x * 32;

  // --- Stage the block's cols slab (contiguous 32*K ints) into LDS. ---
  constexpr int SLAB_BYTES = 32 * K * 4;     // 36864
  constexpr int ROUNDS     = SLAB_BYTES / 4096;  // 9 (256 thr * 16 B)
  const char* slab = (const char*)(cols + (size_t)n0 * K);
  const long long avail = ((long long)N * K - (long long)n0 * K) * 4;
#pragma unroll
  for (int r = 0; r < ROUNDS; ++r) {
    const int off  = r * 4096 + t * 16;
    const int goff = (off + 16 <= avail) ? off : 0;   // clamp past end of cols
    __builtin_amdgcn_global_load_lds(
        (const __attribute__((address_space(1))) void*)(slab + goff),
        (__attribute__((address_space(3))) void*)((char*)scols + off),
        16, 0, 0);
  }
  __syncthreads();   // drains vmcnt -> LDS valid

  const int nl = wave * 8 + g;
  const int n  = n0 + nl;
  if (n >= N) return;

  const int*   __restrict__ srow = scols + nl * K;
  const float* __restrict__ vrow = vals + (size_t)n * K;

  f4 acc0 = {0.f, 0.f, 0.f, 0.f};
  f4 acc1 = {0.f, 0.f, 0.f, 0.f};

  const int rot = g * 8;   // bank-spread rotation (multiple of 8 ints)

#pragma unroll 4
  for (int k = 0; k < K; k += 8) {
    int kk = k + rot;
    if (kk >= K) kk -= K;

    const i4 c0 = *reinterpret_cast<const i4*>(srow + kk);      // ds_read_b128
    const i4 c1 = *reinterpret_cast<const i4*>(srow + kk + 4);
    const f4 v0 = *reinterpret_cast<const f4*>(vrow + kk);
    const f4 v1 = *reinterpret_cast<const f4*>(vrow + kk + 4);

    const f4 x0 = *reinterpret_cast<const f4*>(xT + (size_t)c0.x * B + bq * 4);
    const f4 x1 = *reinterpret_cast<const f4*>(xT + (size_t)c0.y * B + bq * 4);
    const f4 x2 = *reinterpret_cast<const f4*>(xT + (size_t)c0.z * B + bq * 4);
    const f4 x3 = *reinterpret_cast<const f4*>(xT + (size_t)c0.w * B + bq * 4);
    const f4 x4 = *reinterpret_cast<const f4*>(xT + (size_t)c1.x * B + bq * 4);
    const f4 x5 = *reinterpret_cast<const f4*>(xT + (size_t)c1.y * B + bq * 4);
    const f4 x6 = *reinterpret_cast<const f4*>(xT + (size_t)c1.z * B + bq * 4);
    const f4 x7 = *reinterpret_cast<const f4*>(xT + (size_t)c1.w * B + bq * 4);

    acc0 += x0 * v0.x;
    acc0 += x1 * v0.y;
    acc0 += x2 * v0.z;
    acc0 += x3 * v0.w;
    acc1 += x4 * v1.x;
    acc1 += x5 * v1.y;
    acc1 += x6 * v1.z;
    acc1 += x7 * v1.w;
  }

  acc0 += acc1;
  *reinterpret_cast<f4*>(yT + (size_t)n * B + bq * 4) = acc0;
}

// ---------------------------------------------------------------------------
// Kernel 3: transpose yT (N,B) -> y (B,N).
// ---------------------------------------------------------------------------
__global__ __launch_bounds__(256) void transpose_y_kernel(
    const float* __restrict__ yT, float* __restrict__ y) {
  __shared__ float tile[32][33];
  const int n0 = blockIdx.x * 32;
  const int t  = threadIdx.x;
  const int lb = t & 31;
  const int lr = t >> 5;
#pragma unroll
  for (int i = 0; i < 4; ++i) {
    const int nl = lr + i * 8;
    const int n  = n0 + nl;
    float v = 0.f;
    if (n < N) v = yT[(size_t)n * B + lb];   // coalesced over lb
    tile[nl][lb] = v;
  }
  __syncthreads();
#pragma unroll
  for (int i = 0; i < 4; ++i) {
    const int b = lr + i * 8;
    const int n = n0 + lb;
    if (n < N) y[(size_t)b * N + n] = tile[lb][b];  // coalesced over lb
  }
}

// ---------------------------------------------------------------------------
// Fallback (ws too small): direct strided gather, correct but slow.
// ---------------------------------------------------------------------------
__global__ __launch_bounds__(256) void gather_dot_fallback(
    const float* __restrict__ x, const float* __restrict__ vals,
    const int* __restrict__ cols, float* __restrict__ y) {
  const int t    = threadIdx.x;
  const int lane = t & 63;
  const int wave = t >> 6;
  const int g    = lane >> 3;
  const int bq   = lane & 7;
  const int n    = blockIdx.x * 32 + wave * 8 + g;
  if (n >= N) return;
  const int*   crow = cols + (size_t)n * K;
  const float* vrow = vals + (size_t)n * K;
  float4 acc = make_float4(0.f, 0.f, 0.f, 0.f);
  for (int k = 0; k < K; ++k) {
    const int   c = crow[k];
    const float v = vrow[k];
    acc.x += x[(size_t)(bq * 4 + 0) * N + c] * v;
    acc.y += x[(size_t)(bq * 4 + 1) * N + c] * v;
    acc.z += x[(size_t)(bq * 4 + 2) * N + c] * v;
    acc.w += x[(size_t)(bq * 4 + 3) * N + c] * v;
  }
  y[(size_t)(bq * 4 + 0) * N + n] = acc.x;
  y[(size_t)(bq * 4 + 1) * N + n] = acc.y;
  y[(size_t)(bq * 4 + 2) * N + n] = acc.z;
  y[(size_t)(bq * 4 + 3) * N + n] = acc.w;
}

extern "C" void kernel_launch(void* const* d_in, const int* in_sizes, int n_in,
                              void* d_out, int out_size, void* d_ws, size_t ws_size,
                              hipStream_t stream) {
  const float* x    = (const float*)d_in[0];   // x_affine (B,N)
  const float* vals = (const float*)d_in[1];   // (N,K)
  const int*   cols = (const int*)d_in[2];     // (N,K)
  float*       y    = (float*)d_out;           // (B,N)

  const size_t nb_elems = (size_t)N * B;                 // 4.19 MB
  const size_t need     = 2 * nb_elems * sizeof(float);  // xT + yT

  const int nblocks = (N + 31) / 32;   // 1025

  if (ws_size >= need) {
    float* xT = (float*)d_ws;
    float* yT = xT + nb_elems;
    transpose_x_kernel<<<nblocks, 256, 0, stream>>>(x, xT);
    gather_dot_lds_kernel<<<nblocks, 256, 0, stream>>>(xT, vals, cols, yT);
    transpose_y_kernel<<<nblocks, 256, 0, stream>>>(yT, y);
  } else {
    gather_dot_fallback<<<nblocks, 256, 0, stream>>>(x, vals, cols, y);
  }
}